// Round 3
// baseline (187.922 us; speedup 1.0000x reference)
//
#include <hip/hip_runtime.h>

#define EPS_F 1e-7f
#define BONUS 10.0f

typedef float v4f __attribute__((ext_vector_type(4)));

__global__ __launch_bounds__(256) void quadinterp3d_kernel(
    const float* __restrict__ x, const float* __restrict__ noise,
    float* __restrict__ out, int B, int D, int H, int W)
{
    const int t  = threadIdx.x;
    const int w0 = (blockIdx.x * 256 + t) * 4;   // first of 4 voxels along W
    const int h  = blockIdx.y;
    const int bd = blockIdx.z;
    const int d  = bd % D;
    const int b  = bd / D;
    if (w0 >= W) return;

    const long long HW  = (long long)H * W;
    const long long DHW = (long long)D * HW;

    const int hm = max(h - 1, 0), hp = min(h + 1, H - 1);
    const int dm = max(d - 1, 0), dp = min(d + 1, D - 1);
    const int wl = (w0 == 0) ? 0 : w0 - 1;           // left clamp
    const int wr = (w0 + 4 >= W) ? W - 1 : w0 + 4;   // right clamp

    const float* base = x + (long long)b * DHW;
    const int ds[3] = {dm, d, dp};
    const int hs[3] = {hm, h, hp};

    // 9 rows x 6-float sliding window: [w0-1, w0, w0+1, w0+2, w0+3, w0+4]
    float r[9][6];
#pragma unroll
    for (int i = 0; i < 3; ++i) {
#pragma unroll
        for (int j = 0; j < 3; ++j) {
            const float* row = base + (long long)ds[i] * HW + (long long)hs[j] * W;
            v4f v4 = *(const v4f*)(row + w0);  // 16B-aligned: w0 % 4 == 0
            float* m = r[i * 3 + j];
            m[0] = row[wl];
            m[1] = v4.x; m[2] = v4.y; m[3] = v4.z; m[4] = v4.w;
            m[5] = row[wr];
        }
    }

    // noise is wave-uniform; scalar loads
    float n0 = noise[0], n1 = noise[1], n2 = noise[2];
    float n3 = noise[3], n4 = noise[4], n5 = noise[5];
    float n6 = noise[6], n7 = noise[7], n8 = noise[8];

    v4f od, oh, ow, oy;
    float* pod = (float*)&od; float* poh = (float*)&oh;
    float* pow_ = (float*)&ow; float* poy = (float*)&oy;

#pragma unroll
    for (int k = 0; k < 4; ++k) {
        // v[i][j][kk] = r[i*3+j][k+kk]
        float c = r[4][k + 1];

        float gx = 0.5f * (r[4][k + 2] - r[4][k]);
        float gy = 0.5f * (r[5][k + 1] - r[3][k + 1]);
        float gz = 0.5f * (r[1][k + 1] - r[7][k + 1]);

        float dxx = r[4][k + 2] - 2.0f * c + r[4][k];
        float dyy = r[5][k + 1] - 2.0f * c + r[3][k + 1];
        float dss = r[7][k + 1] - 2.0f * c + r[1][k + 1];
        float dxy = 0.25f * (r[3][k] - r[3][k + 2] - r[5][k] + r[5][k + 2]);
        float dys = 0.25f * (r[6][k + 1] - r[8][k + 1] - r[0][k + 1] + r[2][k + 1]);
        float dxs = 0.25f * (r[7][k] - r[7][k + 2] - r[1][k] + r[1][k + 2]);

        // strict NMS over clamped 27-neighborhood (== -inf-padded pool max)
        float mx = c;
#pragma unroll
        for (int q = 0; q < 9; ++q) {
            mx = fmaxf(mx, r[q][k]);
            mx = fmaxf(mx, r[q][k + 1]);
            mx = fmaxf(mx, r[q][k + 2]);
        }
        bool mask = (c == mx);

        float dx0 = 0.0f, dx1 = 0.0f, dx2 = 0.0f, dy = 0.0f;
        if (mask) {
            float A[3][3], rhs[3];
            A[0][0] = dxx + n0 * EPS_F;
            A[0][1] = dxy + n1 * EPS_F;
            A[0][2] = dxs + n2 * EPS_F;
            A[1][0] = dxy + n3 * EPS_F;
            A[1][1] = dyy + n4 * EPS_F;
            A[1][2] = dys + n5 * EPS_F;
            A[2][0] = dxs + n6 * EPS_F;
            A[2][1] = dys + n7 * EPS_F;
            A[2][2] = dss + n8 * EPS_F;
            rhs[0] = gx; rhs[1] = gy; rhs[2] = gz;

            // 3x3 gesv: partial-pivot Gaussian elimination
            {
                int p = 0; float am = fabsf(A[0][0]);
                if (fabsf(A[1][0]) > am) { am = fabsf(A[1][0]); p = 1; }
                if (fabsf(A[2][0]) > am) { p = 2; }
                if (p != 0) {
#pragma unroll
                    for (int j = 0; j < 3; ++j) { float tt = A[0][j]; A[0][j] = A[p][j]; A[p][j] = tt; }
                    float tt = rhs[0]; rhs[0] = rhs[p]; rhs[p] = tt;
                }
                float m1 = A[1][0] / A[0][0];
                float m2 = A[2][0] / A[0][0];
                A[1][1] -= m1 * A[0][1]; A[1][2] -= m1 * A[0][2]; rhs[1] -= m1 * rhs[0];
                A[2][1] -= m2 * A[0][1]; A[2][2] -= m2 * A[0][2]; rhs[2] -= m2 * rhs[0];
            }
            {
                if (fabsf(A[2][1]) > fabsf(A[1][1])) {
                    float tt;
                    tt = A[1][1]; A[1][1] = A[2][1]; A[2][1] = tt;
                    tt = A[1][2]; A[1][2] = A[2][2]; A[2][2] = tt;
                    tt = rhs[1]; rhs[1] = rhs[2]; rhs[2] = tt;
                }
                float m = A[2][1] / A[1][1];
                A[2][2] -= m * A[1][2]; rhs[2] -= m * rhs[1];
            }
            float s2 = rhs[2] / A[2][2];
            float s1 = (rhs[1] - A[1][2] * s2) / A[1][1];
            float s0 = (rhs[0] - A[0][1] * s1 - A[0][2] * s2) / A[0][0];

            dx0 = -s0; dx1 = -s1; dx2 = -s2;
            float amax = fmaxf(fabsf(dx0), fmaxf(fabsf(dx1), fabsf(dx2)));
            if (amax > 0.7f) { dx0 = 0.0f; dx1 = 0.0f; dx2 = 0.0f; }
            dy = 0.5f * (gx * dx0 + gy * dx1 + gz * dx2);
        }

        pod[k] = (float)d + dx2;
        poh[k] = (float)h + dx1;
        pow_[k] = (float)(w0 + k) + dx0;
        poy[k] = c + dy + (mask ? BONUS : 0.0f);
    }

    const long long spatial = (long long)d * HW + (long long)h * W + w0;
    float* oc = out + (long long)b * 3 * DHW + spatial;
    __builtin_nontemporal_store(od, (v4f*)(oc));
    __builtin_nontemporal_store(oh, (v4f*)(oc + DHW));
    __builtin_nontemporal_store(ow, (v4f*)(oc + 2 * DHW));
    float* oyp = out + (long long)B * 3 * DHW + (long long)b * DHW + spatial;
    __builtin_nontemporal_store(oy, (v4f*)(oyp));
}

extern "C" void kernel_launch(void* const* d_in, const int* in_sizes, int n_in,
                              void* d_out, int out_size, void* d_ws, size_t ws_size,
                              hipStream_t stream) {
    const float* x     = (const float*)d_in[0];
    const float* noise = (const float*)d_in[1];
    float* out = (float*)d_out;

    const int B = 2, D = 4, H = 1024, W = 1024;

    dim3 block(256, 1, 1);
    dim3 grid(W / (256 * 4), H, B * D);  // (1, 1024, 8)
    quadinterp3d_kernel<<<grid, block, 0, stream>>>(x, noise, out, B, D, H, W);
}

// Round 4
// 186.915 us; speedup vs baseline: 1.0054x; 1.0054x over previous
//
#include <hip/hip_runtime.h>

#define EPS_F 1e-7f
#define BONUS 10.0f

typedef float v4f __attribute__((ext_vector_type(4)));

__global__ __launch_bounds__(256) void quadinterp3d_kernel(
    const float* __restrict__ x, const float* __restrict__ noise,
    float* __restrict__ out, int B, int D, int H, int W)
{
    const int t  = threadIdx.x;
    const int w0 = (blockIdx.x * 256 + t) * 4;   // first of 4 voxels along W
    const int h  = blockIdx.y;
    const int bd = blockIdx.z;
    const int d  = bd % D;
    const int b  = bd / D;
    if (w0 >= W) return;

    const long long HW  = (long long)H * W;
    const long long DHW = (long long)D * HW;

    const int hm = max(h - 1, 0), hp = min(h + 1, H - 1);
    const int dm = max(d - 1, 0), dp = min(d + 1, D - 1);
    const int wl = (w0 == 0) ? 0 : w0 - 1;           // left clamp
    const int wr = (w0 + 4 >= W) ? W - 1 : w0 + 4;   // right clamp

    const float* base = x + (long long)b * DHW;
    const int ds[3] = {dm, d, dp};
    const int hs[3] = {hm, h, hp};

    // 9 rows x 6-float sliding window: [w0-1, w0, w0+1, w0+2, w0+3, w0+4]
    float r[9][6];
#pragma unroll
    for (int i = 0; i < 3; ++i) {
#pragma unroll
        for (int j = 0; j < 3; ++j) {
            const float* row = base + (long long)ds[i] * HW + (long long)hs[j] * W;
            v4f v4 = *(const v4f*)(row + w0);  // 16B-aligned: w0 % 4 == 0
            float* m = r[i * 3 + j];
            m[0] = row[wl];
            m[1] = v4.x; m[2] = v4.y; m[3] = v4.z; m[4] = v4.w;
            m[5] = row[wr];
        }
    }

    // noise is wave-uniform; scalar loads
    float n0 = noise[0], n1 = noise[1], n2 = noise[2];
    float n3 = noise[3], n4 = noise[4], n5 = noise[5];
    float n6 = noise[6], n7 = noise[7], n8 = noise[8];

    // NMS tree: vertical 9-row max per column, then sliding 3-max.
    float colmax[6];
#pragma unroll
    for (int i = 0; i < 6; ++i) {
        float m = r[0][i];
#pragma unroll
        for (int q = 1; q < 9; ++q) m = fmaxf(m, r[q][i]);
        colmax[i] = m;
    }
    float pmax[5];
#pragma unroll
    for (int i = 0; i < 5; ++i) pmax[i] = fmaxf(colmax[i], colmax[i + 1]);

    // CSE for cross-derivatives along w
    float u35[6], u71[6];
#pragma unroll
    for (int i = 0; i < 6; ++i) {
        u35[i] = r[3][i] - r[5][i];   // dxy_k = 0.25*(u35[k] - u35[k+2])
        u71[i] = r[7][i] - r[1][i];   // dxs_k = 0.25*(u71[k] - u71[k+2])
    }

    v4f od, oh, ow, oy;
    float* pod = (float*)&od; float* poh = (float*)&oh;
    float* pow_ = (float*)&ow; float* poy = (float*)&oy;

#pragma unroll
    for (int k = 0; k < 4; ++k) {
        float c = r[4][k + 1];

        float gx = 0.5f * (r[4][k + 2] - r[4][k]);
        float gy = 0.5f * (r[5][k + 1] - r[3][k + 1]);
        float gz = 0.5f * (r[1][k + 1] - r[7][k + 1]);

        float dxx = r[4][k + 2] - 2.0f * c + r[4][k];
        float dyy = r[5][k + 1] - 2.0f * c + r[3][k + 1];
        float dss = r[7][k + 1] - 2.0f * c + r[1][k + 1];
        float dxy = 0.25f * (u35[k] - u35[k + 2]);
        float dys = 0.25f * (r[6][k + 1] - r[8][k + 1] - r[0][k + 1] + r[2][k + 1]);
        float dxs = 0.25f * (u71[k] - u71[k + 2]);

        float mx = fmaxf(pmax[k], colmax[k + 2]);  // max over clamped 27-nbhd
        bool mask = (c == mx);

        float dx0 = 0.0f, dx1 = 0.0f, dx2 = 0.0f, dy = 0.0f;
        if (mask) {
            float A[3][3], rhs[3];
            A[0][0] = dxx + n0 * EPS_F;
            A[0][1] = dxy + n1 * EPS_F;
            A[0][2] = dxs + n2 * EPS_F;
            A[1][0] = dxy + n3 * EPS_F;
            A[1][1] = dyy + n4 * EPS_F;
            A[1][2] = dys + n5 * EPS_F;
            A[2][0] = dxs + n6 * EPS_F;
            A[2][1] = dys + n7 * EPS_F;
            A[2][2] = dss + n8 * EPS_F;
            rhs[0] = gx; rhs[1] = gy; rhs[2] = gz;

            // 3x3 gesv: partial-pivot Gaussian elimination, v_rcp_f32 divides
            {
                int p = 0; float am = fabsf(A[0][0]);
                if (fabsf(A[1][0]) > am) { am = fabsf(A[1][0]); p = 1; }
                if (fabsf(A[2][0]) > am) { p = 2; }
                if (p != 0) {
#pragma unroll
                    for (int j = 0; j < 3; ++j) { float tt = A[0][j]; A[0][j] = A[p][j]; A[p][j] = tt; }
                    float tt = rhs[0]; rhs[0] = rhs[p]; rhs[p] = tt;
                }
            }
            float ir0 = __builtin_amdgcn_rcpf(A[0][0]);
            float m1 = A[1][0] * ir0;
            float m2 = A[2][0] * ir0;
            A[1][1] -= m1 * A[0][1]; A[1][2] -= m1 * A[0][2]; rhs[1] -= m1 * rhs[0];
            A[2][1] -= m2 * A[0][1]; A[2][2] -= m2 * A[0][2]; rhs[2] -= m2 * rhs[0];

            if (fabsf(A[2][1]) > fabsf(A[1][1])) {
                float tt;
                tt = A[1][1]; A[1][1] = A[2][1]; A[2][1] = tt;
                tt = A[1][2]; A[1][2] = A[2][2]; A[2][2] = tt;
                tt = rhs[1]; rhs[1] = rhs[2]; rhs[2] = tt;
            }
            float ir1 = __builtin_amdgcn_rcpf(A[1][1]);
            float m = A[2][1] * ir1;
            A[2][2] -= m * A[1][2]; rhs[2] -= m * rhs[1];

            float s2 = rhs[2] * __builtin_amdgcn_rcpf(A[2][2]);
            float s1 = (rhs[1] - A[1][2] * s2) * ir1;
            float s0 = (rhs[0] - A[0][1] * s1 - A[0][2] * s2) * ir0;

            dx0 = -s0; dx1 = -s1; dx2 = -s2;
            float amax = fmaxf(fabsf(dx0), fmaxf(fabsf(dx1), fabsf(dx2)));
            if (amax > 0.7f) { dx0 = 0.0f; dx1 = 0.0f; dx2 = 0.0f; }
            dy = 0.5f * (gx * dx0 + gy * dx1 + gz * dx2);
        }

        pod[k] = (float)d + dx2;
        poh[k] = (float)h + dx1;
        pow_[k] = (float)(w0 + k) + dx0;
        poy[k] = c + dy + (mask ? BONUS : 0.0f);
    }

    const long long spatial = (long long)d * HW + (long long)h * W + w0;
    float* oc = out + (long long)b * 3 * DHW + spatial;
    __builtin_nontemporal_store(od, (v4f*)(oc));
    __builtin_nontemporal_store(oh, (v4f*)(oc + DHW));
    __builtin_nontemporal_store(ow, (v4f*)(oc + 2 * DHW));
    float* oyp = out + (long long)B * 3 * DHW + (long long)b * DHW + spatial;
    __builtin_nontemporal_store(oy, (v4f*)(oyp));
}

extern "C" void kernel_launch(void* const* d_in, const int* in_sizes, int n_in,
                              void* d_out, int out_size, void* d_ws, size_t ws_size,
                              hipStream_t stream) {
    const float* x     = (const float*)d_in[0];
    const float* noise = (const float*)d_in[1];
    float* out = (float*)d_out;

    const int B = 2, D = 4, H = 1024, W = 1024;

    dim3 block(256, 1, 1);
    dim3 grid(W / (256 * 4), H, B * D);  // (1, 1024, 8)
    quadinterp3d_kernel<<<grid, block, 0, stream>>>(x, noise, out, B, D, H, W);
}